// Round 1
// 284.468 us; speedup vs baseline: 1.0186x; 1.0186x over previous
//
#include <hip/hip_runtime.h>
#include <math.h>

typedef float f32x4 __attribute__((ext_vector_type(4)));

constexpr int kB = 8;
constexpr int kS = 4096;
constexpr int kF = 128;
constexpr int kT = 16;
constexpr int kNCHUNK = 64;            // S-chunks for the partial reduction
constexpr int kSCHUNK = kS / kNCHUNK;  // 64 s-steps per chunk

// ---------------- Kernel A1: partial sums of diff / diff^2 per (chunk,b,f) ----
// UNCHANGED from the 290 µs version (bit-exact, absmax 0.0).
__global__ __launch_bounds__(128) void std_partial_kernel(
    const float* __restrict__ x, double* __restrict__ psum, double* __restrict__ psq) {
    const int b = blockIdx.x / kNCHUNK;
    const int c = blockIdx.x % kNCHUNK;
    const int f = threadIdx.x;  // 0..127
    const long base = ((long)(b * kS + c * kSCHUNK)) * kF + f;
    // prev for first element of chunk: for global s==0 the reference diff is 0,
    // which falls out of prev = x[s=0] (cur - prev == 0).
    float prev = (c == 0) ? x[(long)b * kS * kF + f] : x[base - kF];
    double s1 = 0.0, s2 = 0.0;
    #pragma unroll 4
    for (int j = 0; j < kSCHUNK; ++j) {
        float cur = x[base + (long)j * kF];
        float d = cur - prev;   // exact f32 diff, matches reference bit-for-bit
        s1 += (double)d;
        s2 += (double)d * (double)d;
        prev = cur;
    }
    const int o = c * (kB * kF) + b * kF + f;
    psum[o] = s1;
    psq[o]  = s2;
}

// ---------------- Kernel A2: finish std, store denom = std_f32 + 1e-8f -------
// UNCHANGED.
__global__ __launch_bounds__(256) void std_finish_kernel(
    const double* __restrict__ psum, const double* __restrict__ psq,
    float* __restrict__ denom) {
    const int i = blockIdx.x * blockDim.x + threadIdx.x;  // [0, kB*kF)
    if (i >= kB * kF) return;
    double s1 = 0.0, s2 = 0.0;
    #pragma unroll 8
    for (int c = 0; c < kNCHUNK; ++c) {
        s1 += psum[c * (kB * kF) + i];
        s2 += psq[c * (kB * kF) + i];
    }
    const double mean = s1 / (double)kS;
    double var = s2 / (double)kS - mean * mean;
    if (var < 0.0) var = 0.0;
    const float stdf = (float)sqrt(var);   // np.std returns f32; double->f32 once
    denom[i] = stdf + 1e-8f;               // f32 add, matches (std + EPS) in f32
}

// ---------------- Fallback: direct std if ws too small (deterministic, slow) -
__global__ __launch_bounds__(128) void std_direct_kernel(
    const float* __restrict__ x, float* __restrict__ denom) {
    const int b = blockIdx.x;
    const int f = threadIdx.x;
    const long base = (long)b * kS * kF + f;
    float prev = x[base];
    double s1 = 0.0, s2 = 0.0;
    for (int s = 0; s < kS; ++s) {
        float cur = x[base + (long)s * kF];
        float d = cur - prev;
        s1 += (double)d;
        s2 += (double)d * (double)d;
        prev = cur;
    }
    const double mean = s1 / (double)kS;
    double var = s2 / (double)kS - mean * mean;
    if (var < 0.0) var = 0.0;
    denom[b * kF + f] = (float)sqrt(var) + 1e-8f;
}

// ---------------- Kernel B (NEW): linear-order output writer -----------------
// One f32x4 of OUT per thread, grid ordered by output address — the write
// stream is sequential exactly like fillBufferAligned (measured 6.3 TB/s).
// Linear f32x4 index i over out[b][t][s][f]:
//   f4 = i & 31          (bits 0..4)   — 32 float4 along F
//   s  = (i>>5)  & 4095  (bits 5..16)
//   t  = (i>>17) & 15    (bits 17..20)
//   b  = i >> 21
// tid only touches bits 0..7, so t, b, phase are uniform per 256-thread block:
// each block writes one contiguous 4 KB run of a single t-slice, and the
// phase branch is wave-uniform (no divergence). x (16.8 MB) is re-read once
// per active t-slice but is L3-resident; prev shares lines with neighbor cur.
__global__ __launch_bounds__(256) void spike_linear_kernel(
    const float* __restrict__ x, const float* __restrict__ denom,
    float* __restrict__ out) {
    const int i  = blockIdx.x * 256 + threadIdx.x;   // f32x4 index, < 2^24
    const int f4 = i & 31;
    const int s  = (i >> 5) & (kS - 1);
    const int t  = (i >> 17) & (kT - 1);
    const int b  = i >> 21;
    const int ph = t % 3;   // 0 -> pos, 1 -> neg, 2 -> silent (block-uniform)

    f32x4 v;
    v[0] = 0.0f; v[1] = 0.0f; v[2] = 0.0f; v[3] = 0.0f;
    if (ph != 2) {
        const long inoff = ((long)(b * kS + s)) * kF + f4 * 4;
        const f32x4 cur  = *(const f32x4*)(x + inoff);
        const f32x4 prev = (s == 0) ? cur : *(const f32x4*)(x + inoff - kF);
        const f32x4 dn   = *(const f32x4*)(denom + b * kF + f4 * 4);
        #pragma unroll
        for (int k = 0; k < 4; ++k) {
            const float nd = (cur[k] - prev[k]) / dn[k];  // f32 div, like reference
            const float sv = (ph == 0) ? nd : -nd;        // exact sign flip
            v[k] = (sv >= 0.1f) ? 1.0f : 0.0f;
        }
    }
    __builtin_nontemporal_store(v, (f32x4*)(out + ((long)i << 2)));
}

extern "C" void kernel_launch(void* const* d_in, const int* in_sizes, int n_in,
                              void* d_out, int out_size, void* d_ws, size_t ws_size,
                              hipStream_t stream) {
    const float* x = (const float*)d_in[0];
    float* out = (float*)d_out;

    // ws layout: [0,4KB) denom floats (1024); then 8B-aligned partial doubles
    float* denom = (float*)d_ws;
    double* psum = (double*)((char*)d_ws + 4096);
    double* psq  = psum + (size_t)kNCHUNK * kB * kF;
    const size_t needed = 4096 + 2ull * kNCHUNK * kB * kF * sizeof(double);

    if (ws_size >= needed) {
        std_partial_kernel<<<kB * kNCHUNK, 128, 0, stream>>>(x, psum, psq);
        std_finish_kernel<<<(kB * kF + 255) / 256, 256, 0, stream>>>(psum, psq, denom);
    } else {
        std_direct_kernel<<<kB, 128, 0, stream>>>(x, denom);
    }

    // total f32x4 in out = 8*16*4096*128/4 = 16,777,216 -> 65536 blocks x 256
    const int n4 = kB * kT * kS * kF / 4;
    spike_linear_kernel<<<n4 / 256, 256, 0, stream>>>(x, denom, out);
}

// Round 2
// 274.738 us; speedup vs baseline: 1.0547x; 1.0354x over previous
//
#include <hip/hip_runtime.h>
#include <math.h>

typedef float f32x4 __attribute__((ext_vector_type(4)));

constexpr int kB = 8;
constexpr int kS = 4096;
constexpr int kF = 128;
constexpr int kT = 16;
constexpr int kNCHUNK = 256;           // S-chunks for the partial reduction (8 blocks/CU)
constexpr int kSCHUNK = kS / kNCHUNK;  // 16 s-steps per chunk

// ---------------- Kernel A1: partial sums of diff / diff^2 per (chunk,b,f) ----
// kNCHUNK 64 -> 256: 2048 blocks (8/CU) for latency hiding. Same exact f32
// diff + f64 accumulation -> same f32 std after finish.
__global__ __launch_bounds__(128) void std_partial_kernel(
    const float* __restrict__ x, double* __restrict__ psum, double* __restrict__ psq) {
    const int b = blockIdx.x / kNCHUNK;
    const int c = blockIdx.x % kNCHUNK;
    const int f = threadIdx.x;  // 0..127
    const long base = ((long)(b * kS + c * kSCHUNK)) * kF + f;
    // prev for first element of chunk: for global s==0 the reference diff is 0,
    // which falls out of prev = x[s=0] (cur - prev == 0).
    float prev = (c == 0) ? x[(long)b * kS * kF + f] : x[base - kF];
    double s1 = 0.0, s2 = 0.0;
    #pragma unroll
    for (int j = 0; j < kSCHUNK; ++j) {
        float cur = x[base + (long)j * kF];
        float d = cur - prev;   // exact f32 diff, matches reference bit-for-bit
        s1 += (double)d;
        s2 += (double)d * (double)d;
        prev = cur;
    }
    const int o = c * (kB * kF) + b * kF + f;
    psum[o] = s1;
    psq[o]  = s2;
}

// ---------------- Kernel A2: finish std, 1024 blocks x 1 wave ---------------
// One block per (b,f); 64 lanes each sum kNCHUNK/64 chunks, then f64
// butterfly reduce. f64 accumulation (~1e-13 rel err) -> f32 cast is
// insensitive to summation order; matches reference like rounds 0/1.
__global__ __launch_bounds__(64) void std_finish_kernel(
    const double* __restrict__ psum, const double* __restrict__ psq,
    float* __restrict__ denom) {
    const int i = blockIdx.x;        // 0..kB*kF-1
    const int lane = threadIdx.x;    // 0..63
    double s1 = 0.0, s2 = 0.0;
    #pragma unroll
    for (int j = 0; j < kNCHUNK / 64; ++j) {
        const long o = (long)(lane + j * 64) * (kB * kF) + i;
        s1 += psum[o];
        s2 += psq[o];
    }
    #pragma unroll
    for (int m = 32; m >= 1; m >>= 1) {
        s1 += __shfl_xor(s1, m, 64);
        s2 += __shfl_xor(s2, m, 64);
    }
    if (lane == 0) {
        const double mean = s1 / (double)kS;
        double var = s2 / (double)kS - mean * mean;
        if (var < 0.0) var = 0.0;
        const float stdf = (float)sqrt(var);   // double->f32 once, like np.std
        denom[i] = stdf + 1e-8f;               // f32 add, matches (std + EPS)
    }
}

// ---------------- Fallback: direct std if ws too small (deterministic, slow) -
__global__ __launch_bounds__(128) void std_direct_kernel(
    const float* __restrict__ x, float* __restrict__ denom) {
    const int b = blockIdx.x;
    const int f = threadIdx.x;
    const long base = (long)b * kS * kF + f;
    float prev = x[base];
    double s1 = 0.0, s2 = 0.0;
    for (int s = 0; s < kS; ++s) {
        float cur = x[base + (long)s * kF];
        float d = cur - prev;
        s1 += (double)d;
        s2 += (double)d * (double)d;
        prev = cur;
    }
    const double mean = s1 / (double)kS;
    double var = s2 / (double)kS - mean * mean;
    if (var < 0.0) var = 0.0;
    denom[b * kF + f] = (float)sqrt(var) + 1e-8f;
}

// ---------------- Kernel B: linear-order writer, PLAIN stores ----------------
// Round-1 showed write ORDER doesn't matter (strided vs linear identical).
// The remaining difference vs the 6.3 TB/s fill is the nontemporal flag,
// which bypasses L2 write-combining. This round: plain f32x4 stores.
// Linear f32x4 index i over out[b][t][s][f]:
//   f4 = i & 31; s = (i>>5) & 4095; t = (i>>17) & 15; b = i >> 21
// t, b, phase are block-uniform (tid only touches bits 0..7): no divergence,
// each block writes one contiguous 4 KB run.
__global__ __launch_bounds__(256) void spike_linear_kernel(
    const float* __restrict__ x, const float* __restrict__ denom,
    float* __restrict__ out) {
    const int i  = blockIdx.x * 256 + threadIdx.x;   // f32x4 index, < 2^24
    const int f4 = i & 31;
    const int s  = (i >> 5) & (kS - 1);
    const int t  = (i >> 17) & (kT - 1);
    const int b  = i >> 21;
    const int ph = t % 3;   // 0 -> pos, 1 -> neg, 2 -> silent (block-uniform)

    f32x4 v;
    v[0] = 0.0f; v[1] = 0.0f; v[2] = 0.0f; v[3] = 0.0f;
    if (ph != 2) {
        const long inoff = ((long)(b * kS + s)) * kF + f4 * 4;
        const f32x4 cur  = *(const f32x4*)(x + inoff);
        const f32x4 prev = (s == 0) ? cur : *(const f32x4*)(x + inoff - kF);
        const f32x4 dn   = *(const f32x4*)(denom + b * kF + f4 * 4);
        #pragma unroll
        for (int k = 0; k < 4; ++k) {
            const float nd = (cur[k] - prev[k]) / dn[k];  // f32 div, like reference
            const float sv = (ph == 0) ? nd : -nd;        // exact sign flip
            v[k] = (sv >= 0.1f) ? 1.0f : 0.0f;
        }
    }
    *(f32x4*)(out + ((long)i << 2)) = v;   // plain store (fill-style, through L2)
}

extern "C" void kernel_launch(void* const* d_in, const int* in_sizes, int n_in,
                              void* d_out, int out_size, void* d_ws, size_t ws_size,
                              hipStream_t stream) {
    const float* x = (const float*)d_in[0];
    float* out = (float*)d_out;

    // ws layout: [0,4KB) denom floats (1024); then 8B-aligned partial doubles
    float* denom = (float*)d_ws;
    double* psum = (double*)((char*)d_ws + 4096);
    double* psq  = psum + (size_t)kNCHUNK * kB * kF;
    const size_t needed = 4096 + 2ull * kNCHUNK * kB * kF * sizeof(double);

    if (ws_size >= needed) {
        std_partial_kernel<<<kB * kNCHUNK, 128, 0, stream>>>(x, psum, psq);
        std_finish_kernel<<<kB * kF, 64, 0, stream>>>(psum, psq, denom);
    } else {
        std_direct_kernel<<<kB, 128, 0, stream>>>(x, denom);
    }

    // total f32x4 in out = 8*16*4096*128/4 = 16,777,216 -> 65536 blocks x 256
    const int n4 = kB * kT * kS * kF / 4;
    spike_linear_kernel<<<n4 / 256, 256, 0, stream>>>(x, denom, out);
}